// Round 6
// baseline (237.705 us; speedup 1.0000x reference)
//
#include <hip/hip_runtime.h>

typedef __attribute__((ext_vector_type(4))) float f32x4;
typedef __attribute__((ext_vector_type(8))) short s16x8;
typedef __attribute__((ext_vector_type(8))) unsigned short u16x8;
typedef __attribute__((address_space(1))) unsigned int g_uint;
typedef __attribute__((address_space(3))) unsigned int lds_uint;

#define T_LEN 2048
#define ENC_D 1024
#define ATT_D 512
#define CONV_C 10

static __device__ __forceinline__ unsigned short f2bf(float f) {
  unsigned int u = __float_as_uint(f);
  u += 0x7FFFu + ((u >> 16) & 1u);
  return (unsigned short)(u >> 16);
}

static __device__ __forceinline__ void gload16(const void* g, void* l) {
  __builtin_amdgcn_global_load_lds((const g_uint*)g, (lds_uint*)l, 16, 0, 0);
}

// ---------------- K0a: Wt2 tiled+swizzled: tile(h,kt)[involution layout] ----------------
// Element (a 0..511, k 0..1023) -> tile (h=a>>8, kt=k>>5), within-tile short offset:
//   (a'>>3)*256 + q*64 + ((a'&7)^q)*8 + (k&7)   where a'=a&255, q=(k>>3)&3
__global__ void k_wt(const float* __restrict__ W, unsigned short* __restrict__ Wt2) {
  __shared__ float tile[64][65];
  int k0 = blockIdx.x * 64, a0 = blockIdx.y * 64;
  int tid = threadIdx.x;
  int r = tid >> 2, cg = tid & 3;
  #pragma unroll
  for (int i = 0; i < 4; ++i) {
    f32x4 v = *reinterpret_cast<const f32x4*>(&W[(size_t)(k0 + r) * ATT_D + a0 + cg * 16 + i * 4]);
    tile[r][cg * 16 + i * 4 + 0] = v[0];
    tile[r][cg * 16 + i * 4 + 1] = v[1];
    tile[r][cg * 16 + i * 4 + 2] = v[2];
    tile[r][cg * 16 + i * 4 + 3] = v[3];
  }
  __syncthreads();
  int r2 = tid >> 2, kg = tid & 3;
  u16x8 o0, o1;
  #pragma unroll
  for (int j = 0; j < 8; ++j) o0[j] = f2bf(tile[kg * 16 + j][r2]);
  #pragma unroll
  for (int j = 0; j < 8; ++j) o1[j] = f2bf(tile[kg * 16 + 8 + j][r2]);
  int a = a0 + r2;            // 0..511
  int k = k0 + kg * 16;       // 16-aligned
  int h = a >> 8, ap = a & 255;
  int kt = k >> 5;
  int q0 = (k >> 3) & 3, q1 = q0 + 1;   // k+8 stays in same kt, q0 in {0,2}
  size_t tbase = ((size_t)h * 32 + kt) * 8192 + (ap >> 3) * 256;
  int sw = ap & 7;
  *reinterpret_cast<u16x8*>(&Wt2[tbase + q0 * 64 + (sw ^ q0) * 8]) = o0;
  *reinterpret_cast<u16x8*>(&Wt2[tbase + q1 * 64 + (sw ^ q1) * 8]) = o1;
}

// ---------------- K0b: f_out[n][c][t] = conv129(ali_prev) + F_b ----------------
__global__ void k_conv(const float* __restrict__ ali, const float* __restrict__ Fw,
                       const float* __restrict__ Fb, float* __restrict__ fout) {
  int b = blockIdx.x;
  int tb = b & 7, nc = b >> 3;
  int c = nc % CONV_C, n = nc / CONV_C;
  __shared__ float sa[384];
  __shared__ float sw[129];
  int tid = threadIdx.x;
  int t0 = tb * 256;
  for (int i = tid; i < 384; i += 256) {
    int t = t0 - 64 + i;
    sa[i] = (t >= 0 && t < T_LEN) ? ali[n * T_LEN + t] : 0.f;
  }
  if (tid < 129) sw[tid] = Fw[c * 129 + tid];
  __syncthreads();
  float acc = Fb[c];
  #pragma unroll 8
  for (int k = 0; k < 129; ++k) acc += sw[k] * sa[tid + k];
  fout[(size_t)(n * CONV_C + c) * T_LEN + t0 + tid] = acc;
}

// ---------------- K0c: dec_ws[n][a] = dec_prev[n]@W_dec[:,a] + b_enc[a] ----------------
__global__ void k_dec(const float* __restrict__ dec_prev, const float* __restrict__ Wd,
                      const float* __restrict__ benc, float* __restrict__ dec_ws) {
  int b = blockIdx.x;
  int n = b >> 1, half = b & 1;
  int a = half * 256 + threadIdx.x;
  __shared__ float sd[1024];
  for (int i = threadIdx.x; i < 1024; i += 256) sd[i] = dec_prev[n * 1024 + i];
  __syncthreads();
  float acc = benc[a];
  #pragma unroll 8
  for (int d = 0; d < 1024; ++d) acc += sd[d] * Wd[(size_t)d * ATT_D + a];
  dec_ws[n * ATT_D + a] = acc;
}

// ---------------- K1: fused score GEMM (BM=128, BN=256-half, BK=32, 8 waves) ----------------
// T2 involution LDS layout (conflict-free frag reads), T3/T4 counted-vmcnt 3-buffer
// pipeline with issue-after-barrier, T5 setprio around MFMA cluster.
__global__ __launch_bounds__(512, 4) void k_score(
    const float* __restrict__ enc, const unsigned short* __restrict__ Wt2,
    const float* __restrict__ fout, const float* __restrict__ dec_ws,
    const float* __restrict__ W_att, const float* __restrict__ w_vec,
    float* __restrict__ score_ws) {
  __shared__ __align__(16) char smem[73728];   // 3 x (B 16384 + A 8192)

  int bid = blockIdx.x;             // nwg = 1024 (512 mt x 2 h), 1024 % 8 == 0
  int xcd = bid & 7, idx = bid >> 3;
  int mt = xcd * 64 + (idx >> 1);   // pair h-blocks of same mt on one XCD (A L2 reuse)
  int h = idx & 1;

  int tid = threadIdx.x;
  int w = tid >> 6, lane = tid & 63;
  int l15 = lane & 15, q = lane >> 4;
  int wm = w >> 2, wn = w & 3;      // wave tile 64(M) x 64(N)

  // A staging: thread -> (row = tid>>2, 8 f32 at col (tid&3)*8)
  int arow = tid >> 2, aq = tid & 3;
  const float* Asrc = enc + ((size_t)mt * 128 + arow) * ENC_D + aq * 8;
  // B staging: linear copy of pre-tiled+swizzled 16KB tile
  const unsigned short* Bsrc = Wt2 + (size_t)h * 32 * 8192 + tid * 8;

  // involution-layout offsets (bytes)
  int awoff = 16384 + (arow >> 3) * 512 + aq * 128 + ((arow & 7) ^ aq) * 16;
  int swl = (l15 & 7) ^ q;
  int aql = 16384 + (wm * 8 + (l15 >> 3)) * 512 + q * 128 + swl * 16;
  int bql = (wn * 8 + (l15 >> 3)) * 512 + q * 128 + swl * 16;

  f32x4 acc[4][4];
  #pragma unroll
  for (int m = 0; m < 4; ++m)
    #pragma unroll
    for (int nf = 0; nf < 4; ++nf)
      acc[m][nf] = (f32x4){0.f, 0.f, 0.f, 0.f};

  f32x4 r0a, r0b, r1a, r1b;   // two A prefetch slots (static names)

  auto issueA = [&](int kt, f32x4& x0, f32x4& x1) {
    const float* p = Asrc + kt * 32;
    x0 = *reinterpret_cast<const f32x4*>(p);
    x1 = *reinterpret_cast<const f32x4*>(p + 4);
  };
  auto issueB = [&](int kt, char* buf) {
    const unsigned short* s = Bsrc + (size_t)kt * 8192;
    gload16(s, buf + tid * 16);
    gload16(s + 4096, buf + tid * 16 + 8192);
  };
  auto writeA = [&](f32x4& x0, f32x4& x1, char* buf) {
    union { u16x8 v; unsigned int u[4]; } pk;
    asm("v_cvt_pk_bf16_f32 %0, %1, %2" : "=v"(pk.u[0]) : "v"(x0[0]), "v"(x0[1]));
    asm("v_cvt_pk_bf16_f32 %0, %1, %2" : "=v"(pk.u[1]) : "v"(x0[2]), "v"(x0[3]));
    asm("v_cvt_pk_bf16_f32 %0, %1, %2" : "=v"(pk.u[2]) : "v"(x1[0]), "v"(x1[1]));
    asm("v_cvt_pk_bf16_f32 %0, %1, %2" : "=v"(pk.u[3]) : "v"(x1[2]), "v"(x1[3]));
    *reinterpret_cast<u16x8*>(buf + awoff) = pk.v;
  };
  auto compute = [&](const char* buf) {
    s16x8 af[4];
    #pragma unroll
    for (int m = 0; m < 4; ++m)
      af[m] = *reinterpret_cast<const s16x8*>(buf + aql + m * 1024);
    __builtin_amdgcn_s_setprio(1);
    #pragma unroll
    for (int i = 0; i < 4; ++i) {
      s16x8 bfr = *reinterpret_cast<const s16x8*>(buf + bql + i * 1024);
      #pragma unroll
      for (int m = 0; m < 4; ++m)
        acc[m][i] = __builtin_amdgcn_mfma_f32_16x16x32_bf16(af[m], bfr, acc[m][i], 0, 0, 0);
    }
    __builtin_amdgcn_s_setprio(0);
  };

  // ---- prologue: stage k=0 and k=1 ----
  issueB(0, smem);
  issueA(0, r0a, r0b);
  issueB(1, smem + 24576);
  issueA(1, r1a, r1b);
  writeA(r0a, r0b, smem);           // compiler inserts counted vmcnt for A(0) regs

  // ---- main loop: 1 barrier per K-step, loads span barriers ----
  #pragma unroll
  for (int k = 0; k < 32; ++k) {
    char* bc = smem + (k % 3) * 24576;
    char* bn = smem + ((k + 1) % 3) * 24576;
    char* b2 = smem + ((k + 2) % 3) * 24576;
    asm volatile("s_waitcnt vmcnt(6) lgkmcnt(0)" ::: "memory");
    __builtin_amdgcn_sched_barrier(0);
    __builtin_amdgcn_s_barrier();
    if (k + 2 < 32) {
      issueB(k + 2, b2);
      if ((k & 1) == 0) issueA(k + 2, r0a, r0b);
      else              issueA(k + 2, r1a, r1b);
    }
    compute(bc);
    if (k + 1 < 32) {
      if ((k & 1) == 0) writeA(r1a, r1b, bn);
      else              writeA(r0a, r0b, bn);
    }
  }
  __syncthreads();

  // ---- epilogue: att mix + dec + tanh + dot(w) + row-reduce ----
  float* f_lds = (float*)smem;               // [10][128] = 5120
  float* attw  = (float*)(smem + 5120);      // [256][10] = 10240
  float* d_lds = (float*)(smem + 15360);     // [256]
  float* w_lds = (float*)(smem + 16384);     // [256]
  float* red   = (float*)(smem + 17408);     // [8][64] = 2048

  int n = mt >> 4;
  int t0 = (mt & 15) * 128;

  for (int i = tid; i < 1280; i += 512) {
    int c = i >> 7, tt = i & 127;
    f_lds[c * 128 + tt] = fout[(size_t)(n * CONV_C + c) * T_LEN + t0 + tt];
  }
  for (int i = tid; i < 2560; i += 512) attw[i] = W_att[h * 2560 + i];
  if (tid < 256) {
    d_lds[tid] = dec_ws[n * ATT_D + h * 256 + tid];
    w_lds[tid] = w_vec[h * 256 + tid];
  }
  __syncthreads();

  #pragma unroll
  for (int m = 0; m < 4; ++m) {
    #pragma unroll
    for (int j = 0; j < 4; ++j) {
      int tt = wm * 64 + m * 16 + q * 4 + j;
      float s = 0.f;
      #pragma unroll
      for (int nf = 0; nf < 4; ++nf) {
        int cl = wn * 64 + nf * 16 + l15;
        float att = 0.f;
        #pragma unroll
        for (int c = 0; c < CONV_C; ++c) att += f_lds[c * 128 + tt] * attw[cl * CONV_C + c];
        float x = acc[m][nf][j] + d_lds[cl] + att;
        float e = __expf(2.f * x);
        float th = 1.f - 2.f / (e + 1.f);
        s += w_lds[cl] * th;
      }
      float v = s;
      v += __shfl_xor(v, 1);
      v += __shfl_xor(v, 2);
      v += __shfl_xor(v, 4);
      v += __shfl_xor(v, 8);
      if (l15 == 0) red[w * 64 + m * 16 + q * 4 + j] = v;
    }
  }
  __syncthreads();
  if (tid < 128) {
    int wm2 = tid >> 6, lr = tid & 63;
    float s = red[(wm2 * 4 + 0) * 64 + lr] + red[(wm2 * 4 + 1) * 64 + lr]
            + red[(wm2 * 4 + 2) * 64 + lr] + red[(wm2 * 4 + 3) * 64 + lr];
    score_ws[(size_t)h * 65536 + (size_t)mt * 128 + tid] = s;
  }
}

// ---------------- K2: masked softmax over T per row ----------------
__global__ void k_softmax(const float* __restrict__ score_ws, const int* __restrict__ enc_len,
                          float* __restrict__ ali_out) {
  __shared__ float wmx[4], wsum[4];
  int n = blockIdx.x, tid = threadIdx.x;
  int len = enc_len[n];
  int w = tid >> 6, lane = tid & 63;
  float s[8], e[8];
  float mx = -1e30f;
  #pragma unroll
  for (int i = 0; i < 8; ++i) {
    int t = i * 256 + tid;
    float v = score_ws[n * T_LEN + t] + score_ws[65536 + n * T_LEN + t];
    s[i] = v;
    if (t < len) mx = fmaxf(mx, v);
  }
  #pragma unroll
  for (int off = 32; off; off >>= 1) mx = fmaxf(mx, __shfl_xor(mx, off));
  if (lane == 0) wmx[w] = mx;
  __syncthreads();
  mx = fmaxf(fmaxf(wmx[0], wmx[1]), fmaxf(wmx[2], wmx[3]));
  float sum = 0.f;
  #pragma unroll
  for (int i = 0; i < 8; ++i) {
    int t = i * 256 + tid;
    float v = (t < len) ? __expf(s[i] - mx) : 0.f;
    e[i] = v;
    sum += v;
  }
  #pragma unroll
  for (int off = 32; off; off >>= 1) sum += __shfl_xor(sum, off);
  if (lane == 0) wsum[w] = sum;
  __syncthreads();
  sum = wsum[0] + wsum[1] + wsum[2] + wsum[3];
  float inv = 1.f / sum;
  #pragma unroll
  for (int i = 0; i < 8; ++i) ali_out[n * T_LEN + i * 256 + tid] = e[i] * inv;
}

// ---------------- K3: ctx partials over T-chunks ----------------
__global__ void k_ctx(const float* __restrict__ ali, const float* __restrict__ enc,
                      float* __restrict__ part) {
  int b = blockIdx.x;                   // n*32 + tc
  int n = b >> 5, tc = b & 31;
  int tid = threadIdx.x;
  f32x4 acc = (f32x4){0.f, 0.f, 0.f, 0.f};
  const float* ep = enc + (size_t)(n * T_LEN + tc * 64) * ENC_D + tid * 4;
  const float* ap = ali + n * T_LEN + tc * 64;
  #pragma unroll 4
  for (int i = 0; i < 64; ++i) {
    float a = ap[i];
    f32x4 ev = *reinterpret_cast<const f32x4*>(ep + (size_t)i * ENC_D);
    acc += ev * a;
  }
  *reinterpret_cast<f32x4*>(&part[(size_t)b * ENC_D + tid * 4]) = acc;
}

// ---------------- K4: reduce ctx partials ----------------
__global__ void k_ctx_red(const float* __restrict__ part, float* __restrict__ ctx_out) {
  int g = blockIdx.x * 256 + threadIdx.x;
  int n = g >> 10, d = g & 1023;
  float s = 0.f;
  #pragma unroll 8
  for (int tc = 0; tc < 32; ++tc) s += part[(size_t)(n * 32 + tc) * ENC_D + d];
  ctx_out[g] = s;
}

extern "C" void kernel_launch(void* const* d_in, const int* in_sizes, int n_in,
                              void* d_out, int out_size, void* d_ws, size_t ws_size,
                              hipStream_t stream) {
  const float* enc      = (const float*)d_in[0];
  const int*   enc_len  = (const int*)d_in[1];
  const float* dec_prev = (const float*)d_in[2];
  const float* ali_prev = (const float*)d_in[3];
  const float* W_enc    = (const float*)d_in[4];
  const float* b_enc    = (const float*)d_in[5];
  const float* W_dec    = (const float*)d_in[6];
  const float* F_w      = (const float*)d_in[7];
  const float* F_b      = (const float*)d_in[8];
  const float* W_att    = (const float*)d_in[9];
  const float* w_vec    = (const float*)d_in[10];
  float* out = (float*)d_out;

  char* ws = (char*)d_ws;
  unsigned short* Wt2 = (unsigned short*)ws;       // 1,048,576 B (tiled+swizzled)
  float* fout   = (float*)(ws + 1048576);          // 2,621,440 B
  float* dec_ws = (float*)(ws + 3670016);          //    65,536 B
  float* score  = (float*)(ws + 3735552);          //   524,288 B
  float* part   = (float*)(ws + 4259840);          // 4,194,304 B

  hipLaunchKernelGGL(k_wt, dim3(16, 8), dim3(256), 0, stream, W_enc, Wt2);
  hipLaunchKernelGGL(k_conv, dim3(2560), dim3(256), 0, stream, ali_prev, F_w, F_b, fout);
  hipLaunchKernelGGL(k_dec, dim3(64), dim3(256), 0, stream, dec_prev, W_dec, b_enc, dec_ws);
  hipLaunchKernelGGL(k_score, dim3(1024), dim3(512), 0, stream, enc, Wt2, fout, dec_ws, W_att, w_vec, score);
  hipLaunchKernelGGL(k_softmax, dim3(32), dim3(256), 0, stream, score, enc_len, out);
  hipLaunchKernelGGL(k_ctx, dim3(1024), dim3(256), 0, stream, out, enc, part);
  hipLaunchKernelGGL(k_ctx_red, dim3(128), dim3(256), 0, stream, part, out + 65536);
}